// Round 2
// baseline (224.635 us; speedup 1.0000x reference)
//
#include <hip/hip_runtime.h>
#include <math.h>

// Problem constants (from reference)
#define BATCH     2
#define NLAB      256            // 64 bifs * 4 stubs
#define VOX       (192*192*192)  // 7,077,888 voxels per batch
#define VVEC      (VOX/4)        // 1,769,472 float4 per batch
#define TEMP      0.2f

// Hybrid histo: 576 blocks/batch, period-9 role pattern (4 atomic : 5 MFMA).
// 9 is coprime with 8 (XCDs) and 256 (CUs) so any round-robin dispatch gives
// every CU a mix of roles -> ds_add pipe (atomic waves) and VALU (MFMA waves)
// run concurrently. Balance from measured pipe costs (R0/R1):
//   atomic: LDS 2.44 cyc/vox, VALU 0.38 | mfma: LDS 0.94, VALU 2.60
//   -> f_atomic = 4/9 = 0.444, t ~ 1.6 cyc/vox ~ 37 us.
#define BLOCKS    576            // per batch; 576 = 9*64
#define NITER     12             // 576*12*256 = VVEC exact
#define NPART     16             // 576/16 = 36 slots per reduce part
#define NATOMIC_ORDS 256         // 64 groups * 4 atomic blocks
#define MFMA_F4_BASE (NATOMIC_ORDS * NITER * 256)   // 786,432 f4 boundary

// Packed slot: value = sum_fg + STEP*count. Per block 12288 voxels, per-bin
// max ~130 -> packed <= ~540K << 2^24: count decodes exactly; fg rounding
// noise ~1e-4 relative on batch-bin means (threshold 1e-2; R0 absmax 0.0).
#define STEP      4096.0f
#define INV_STEP  (1.0f/4096.0f)

typedef unsigned int u32;
typedef __attribute__((ext_vector_type(8))) short bf16x8;   // 8 bf16 (4 VGPRs)
typedef __attribute__((ext_vector_type(4))) float f32x4;    // MFMA C/D
union FragU { uint4 u; bf16x8 v; };

// fg = softmax(pred, ch)[1] = sigmoid(p1-p0) since C == 2.
__device__ __forceinline__ u32 packvox(float pa, float pc, float pl) {
    const float fg = 1.0f / (1.0f + __expf(pa - pc));
    u32 bits = __float_as_uint(fg);
    bits += 0x7FFFu + ((bits >> 16) & 1u);            // RNE to bf16
    const u32 lab = ((u32)(int)(pl + 0.5f)) & 255u;
    return (lab << 24) | (bits >> 16);
}

// One packed-bf16 word (2 K-slots) of each fragment: A=[hi==m], B1=[lo==m],
// B2=[lo==m]*fg. Verified absmax 0.0 at R1 — unchanged.
#define PAIR(de, dodd, aw, b1w, b2w) do {                                   \
    const u32 _e = (de), _o = (dodd);                                       \
    const bool he  = ((_e >> 28) == mlane);                                 \
    const bool ho  = ((_o >> 28) == mlane);                                 \
    const bool le  = (((_e >> 24) & 15u) == mlane);                         \
    const bool lo_ = (((_o >> 24) & 15u) == mlane);                         \
    aw  = (he ? 0x00003F80u : 0u) | (ho  ? 0x3F800000u : 0u);               \
    b1w = (le ? 0x00003F80u : 0u) | (lo_ ? 0x3F800000u : 0u);               \
    b2w = (le ? (_e & 0xFFFFu) : 0u) | (lo_ ? (_o << 16) : 0u);             \
} while (0)

// ---------------------------------------------------------------------------
// Kernel 1: hybrid histogram. Block role by blockIdx.x % 9:
//   j < 4  -> ATOMIC role (R0 body: one packed ds_add_f32 per valid voxel)
//   j >= 4 -> MFMA role (R1 body: one-hot outer-product, no atomics)
// Both write one packed 256-bin slot. 8 KB LDS (union of both roles).
// ---------------------------------------------------------------------------
__global__ __launch_bounds__(256) void histo_kernel(
    const float* __restrict__ pred,     // [B,2,V]
    const float* __restrict__ labmap,   // [B,1,V]
    float* __restrict__ ws_slots)       // [B*BLOCKS][256] packed per-block hist
{
    __shared__ __align__(16) u32 s_lds[4][2][256];  // 8 KB, role-dependent use

    const int b   = blockIdx.y;
    const int bx  = blockIdx.x;
    const int tid = threadIdx.x;
    const int j   = bx % 9;
    const int grp = bx / 9;

    const float4* p0 = (const float4*)(pred + (size_t)b * 2 * VOX);
    const float4* p1 = (const float4*)(pred + (size_t)b * 2 * VOX + VOX);
    const float4* lm = (const float4*)(labmap + (size_t)b * VOX);

    float val;

    if (j < 4) {
        // ------------------------- ATOMIC role ---------------------------
        // R0-verified: ds_add pipe ~3.3 cyc/active-lane-op; loss-unused
        // labels (stub 0 or bif 0: 26.2%) exec-masked. 2 LDS copies by lane
        // parity halve same-address collisions.
        float* h = (float*)&s_lds[0][0][0];          // 512 floats
        h[tid] = 0.0f;
        h[tid + NLAB] = 0.0f;
        __syncthreads();

        const int ord  = grp * 4 + j;                // 0..255
        const int copy = (tid & 1) << 8;
        const int base = ord * (NITER * 256) + tid;  // contiguous chunk

        #pragma unroll 3
        for (int it = 0; it < NITER; ++it) {
            const int i = base + it * 256;
            const float4 a = p0[i];
            const float4 c = p1[i];
            const float4 l = lm[i];

            float fg0 = 1.0f / (1.0f + __expf(a.x - c.x));
            float fg1 = 1.0f / (1.0f + __expf(a.y - c.y));
            float fg2 = 1.0f / (1.0f + __expf(a.z - c.z));
            float fg3 = 1.0f / (1.0f + __expf(a.w - c.w));

            int l0 = ((int)(l.x + 0.5f)) & (NLAB - 1);
            int l1 = ((int)(l.y + 0.5f)) & (NLAB - 1);
            int l2 = ((int)(l.z + 0.5f)) & (NLAB - 1);
            int l3 = ((int)(l.w + 0.5f)) & (NLAB - 1);

            if ((l0 & 3) && l0 >= 4) atomicAdd(&h[copy + l0], STEP + fg0);
            if ((l1 & 3) && l1 >= 4) atomicAdd(&h[copy + l1], STEP + fg1);
            if ((l2 & 3) && l2 >= 4) atomicAdd(&h[copy + l2], STEP + fg2);
            if ((l3 & 3) && l3 >= 4) atomicAdd(&h[copy + l3], STEP + fg3);
        }
        __syncthreads();
        val = h[tid] + h[tid + NLAB];
    } else {
        // -------------------------- MFMA role ----------------------------
        // R1-verified (absmax 0.0): bin = hi4*16 + lo4; per 32-voxel tile
        // counts += Phi^T*Plo, sums += Phi^T*(fg*Plo), 16x16x32 bf16 MFMA.
        const int w    = tid >> 6;          // wave 0..3
        const int lane = tid & 63;
        const u32 mlane = (u32)(lane & 15);
        const int g    = lane >> 4;

        f32x4 accC = {0.f, 0.f, 0.f, 0.f};
        f32x4 accS = {0.f, 0.f, 0.f, 0.f};

        const int ord  = grp * 5 + (j - 4);          // 0..319
        const int base = MFMA_F4_BASE + ord * (NITER * 256) + tid;

        #pragma unroll 2
        for (int it = 0; it < NITER; ++it) {
            const int i = base + it * 256;
            const float4 a = p0[i];
            const float4 c = p1[i];
            const float4 l = lm[i];

            uint4 pkv;
            pkv.x = packvox(a.x, c.x, l.x);
            pkv.y = packvox(a.y, c.y, l.y);
            pkv.z = packvox(a.z, c.z, l.z);
            pkv.w = packvox(a.w, c.w, l.w);

            u32* st = &s_lds[w][it & 1][0];
            *(uint4*)(st + (lane << 2)) = pkv;   // wave-private: no barrier

            const u32* rp = st + (g << 3);
            #pragma unroll
            for (int t = 0; t < 8; ++t) {
                const uint4 q0 = *(const uint4*)(rp + t * 32);
                const uint4 q1 = *(const uint4*)(rp + t * 32 + 4);
                u32 a0, a1, a2, a3, b10, b11, b12, b13, b20, b21, b22, b23;
                PAIR(q0.x, q0.y, a0, b10, b20);
                PAIR(q0.z, q0.w, a1, b11, b21);
                PAIR(q1.x, q1.y, a2, b12, b22);
                PAIR(q1.z, q1.w, a3, b13, b23);
                FragU A, B1, B2;
                A.u  = make_uint4(a0, a1, a2, a3);
                B1.u = make_uint4(b10, b11, b12, b13);
                B2.u = make_uint4(b20, b21, b22, b23);
                accC = __builtin_amdgcn_mfma_f32_16x16x32_bf16(A.v, B1.v, accC, 0, 0, 0);
                accS = __builtin_amdgcn_mfma_f32_16x16x32_bf16(A.v, B2.v, accS, 0, 0, 0);
            }
        }

        // C/D layout (m89): col = lane&15, row = (lane>>4)*4 + reg.
        // Reuse stage LDS for the cross-wave fold (in-wave ds order is safe).
        float* cnt_w = (float*)&s_lds[w][0][0];
        float* sum_w = (float*)&s_lds[w][1][0];
        const int row0 = (lane >> 4) << 2;
        const int colb = lane & 15;
        #pragma unroll
        for (int jj = 0; jj < 4; ++jj) {
            cnt_w[(row0 + jj) * 16 + colb] = accC[jj];
            sum_w[(row0 + jj) * 16 + colb] = accS[jj];
        }
        __syncthreads();

        float cs = 0.0f, ss = 0.0f;
        #pragma unroll
        for (int ww = 0; ww < 4; ++ww) {
            cs += ((float*)&s_lds[ww][0][0])[tid];
            ss += ((float*)&s_lds[ww][1][0])[tid];
        }
        val = ss + STEP * cs;
    }

    ws_slots[((size_t)(b * BLOCKS + bx)) * NLAB + tid] = val;
}

// ---------------------------------------------------------------------------
// Kernel 2: parallel slot reduction. Block r: batch = r/NPART, part = r%NPART;
// 256 threads = bins. Decode + sum BLOCKS/NPART slots (coalesced 1KB rows).
// ---------------------------------------------------------------------------
__global__ __launch_bounds__(256) void reduce_kernel(
    const float* __restrict__ ws_slots, // [B*BLOCKS][256]
    float* __restrict__ psum,           // [B*NPART][256]
    float* __restrict__ pcnt)           // [B*NPART][256]
{
    const int bin  = threadIdx.x;
    const int b    = blockIdx.x / NPART;
    const int part = blockIdx.x % NPART;
    const int per  = BLOCKS / NPART;

    float cs = 0.0f, ss = 0.0f;
    for (int s = part * per; s < (part + 1) * per; ++s) {
        float v = ws_slots[((size_t)(b * BLOCKS + s)) * NLAB + bin];
        float c = floorf(v * INV_STEP + 0.5f);   // exact count decode
        cs += c;
        ss += v - c * STEP;                      // packed fg sum
    }
    psum[(size_t)blockIdx.x * NLAB + bin] = ss;
    pcnt[(size_t)blockIdx.x * NLAB + bin] = cs;
}

// ---------------------------------------------------------------------------
// Kernel 3: fold partials, then masked softmin -> scalar loss.
// ---------------------------------------------------------------------------
__global__ __launch_bounds__(256) void scalar_kernel(
    const float* __restrict__ psum,     // [B*NPART][256]
    const float* __restrict__ pcnt,
    float* __restrict__ out)            // [1] loss
{
    __shared__ float s_fsum[BATCH][NLAB];
    __shared__ float s_fcnt[BATCH][NLAB];

    const int tid = threadIdx.x;        // 256 threads = bins

    for (int b = 0; b < BATCH; ++b) {
        float ss = 0.0f, cs = 0.0f;
        for (int p = 0; p < NPART; ++p) {
            ss += psum[(size_t)(b * NPART + p) * NLAB + tid];
            cs += pcnt[(size_t)(b * NPART + p) * NLAB + tid];
        }
        s_fsum[b][tid] = ss;
        s_fcnt[b][tid] = cs;
    }
    __syncthreads();

    if (tid < 64) {
        float total = 0.0f;
        float nbifs = 0.0f;
        if (tid >= 1) {  // bifs 1..63 (reference drops bif 0)
            for (int bb = 0; bb < BATCH; ++bb) {
                float means[3];
                bool  valid[3];
                int   nvalid = 0;
                for (int s = 0; s < 3; ++s) {
                    int lab = tid * 4 + 1 + s;   // stub s+1 (stub 0 dropped)
                    float cnt = s_fcnt[bb][lab];
                    float sum = s_fsum[bb][lab];
                    valid[s] = (cnt >= 1.0f);            // MIN_VOXELS = 1
                    means[s] = sum / fmaxf(cnt, 1.0f);
                    nvalid  += valid[s] ? 1 : 0;
                }
                float logits[3], m = -3e38f;
                for (int s = 0; s < 3; ++s) {
                    logits[s] = valid[s] ? (-means[s] / TEMP) : -1e9f;
                    m = fmaxf(m, logits[s]);
                }
                float e[3], se = 0.0f;
                for (int s = 0; s < 3; ++s) { e[s] = __expf(logits[s] - m); se += e[s]; }
                float score = 0.0f;
                for (int s = 0; s < 3; ++s) {
                    if (valid[s]) score += means[s] * (e[s] / se);
                }
                if (nvalid >= 2) {  // MIN_STUBS = 2
                    total += 1.0f - score;
                    nbifs += 1.0f;
                }
            }
        }
        for (int off = 32; off > 0; off >>= 1) {
            total += __shfl_down(total, off);
            nbifs += __shfl_down(nbifs, off);
        }
        if (tid == 0) {
            out[0] = (nbifs > 0.0f) ? (total / fmaxf(nbifs, 1.0f)) : 0.0f;
        }
    }
}

// ---------------------------------------------------------------------------
extern "C" void kernel_launch(void* const* d_in, const int* in_sizes, int n_in,
                              void* d_out, int out_size, void* d_ws, size_t ws_size,
                              hipStream_t stream) {
    const float* pred = (const float*)d_in[0];   // [B,C,D,H,W] fp32
    const float* lab  = (const float*)d_in[1];   // [B,1,D,H,W] fp32

    float* ws_slots = (float*)d_ws;                          // [B*BLOCKS][256]
    float* psum = ws_slots + (size_t)BATCH * BLOCKS * NLAB;  // [B*NPART][256]
    float* pcnt = psum + (size_t)BATCH * NPART * NLAB;       // [B*NPART][256]

    dim3 grid(BLOCKS, BATCH);
    histo_kernel<<<grid, 256, 0, stream>>>(pred, lab, ws_slots);
    reduce_kernel<<<BATCH * NPART, 256, 0, stream>>>(ws_slots, psum, pcnt);
    scalar_kernel<<<1, 256, 0, stream>>>(psum, pcnt, (float*)d_out);
}

// Round 3
// 210.905 us; speedup vs baseline: 1.0651x; 1.0651x over previous
//
#include <hip/hip_runtime.h>
#include <math.h>

// Problem constants (from reference)
#define BATCH     2
#define NLAB      256            // 64 bifs * 4 stubs
#define VOX       (192*192*192)  // 7,077,888 voxels per batch
#define TEMP      0.2f
#define GRIDX     768            // blocks per batch (R1-proven geometry)
#define NITER     ((VOX/4)/(GRIDX*256))   // = 9 exact
#define NPART     16             // reduce parts per batch

// Packed slot: value = sum_fg + STEP*count. Per block 9216 voxels (~36/bin,
// max ~150): packed <= ~600K << 2^24 -> count decodes exactly; fg rounding
// noise ~1e-4 relative on batch-bin means (threshold 1e-2; R1 absmax 0.0).
#define STEP      4096.0f
#define INV_STEP  (1.0f/4096.0f)

typedef unsigned int u32;
typedef __attribute__((ext_vector_type(8))) short bf16x8;   // 8 bf16 (4 VGPRs)
typedef __attribute__((ext_vector_type(4))) float f32x4;    // MFMA C/D
union FragU { uint4 u; bf16x8 v; };

// Per-voxel staging prep: fg = sigmoid(p1-p0) (C==2 softmax ch1), RNE->bf16;
// mask word w0 = (1<<hi) in low16 | (1<<lo) in high16, bin = hi*16+lo.
__device__ __forceinline__ void voxprep(float pa, float pc, float pl,
                                        u32& fg16, u32& w0) {
    const float fg = __builtin_amdgcn_rcpf(1.0f + __expf(pa - pc));
    u32 bits = __float_as_uint(fg);
    bits += 0x7FFFu + ((bits >> 16) & 1u);            // RNE to bf16
    fg16 = bits >> 16;                                // bf16 in low 16
    const u32 lab = ((u32)(int)(pl + 0.5f)) & 255u;
    w0 = (1u << (lab >> 4)) + ((1u << (lab & 15u)) << 16);
}

// Build one packed-bf16 word (2 K-slots: even/odd) of each fragment with
// PURE BIT ARITHMETIC (no cmp/cndmask — R1's 2x VALU bloat source):
//   A  = one-hot(hi==m)*1.0 ; B1 = one-hot(lo==m)*1.0 ; B2 = one-hot(lo==m)*fg
// hpk/lpk in {0,1,0x10000,0x10001}; *0x3F80 plants bf16 1.0 per half;
// *0xFFFF builds a half-select mask for the packed fg pair. Semantics
// identical to R1's verified PAIR (absmax 0.0).
#define PAIR2(w0e, w0o, fp, aw, b1w, b2w) do {                              \
    const u32 _he = ((w0e) >> mlane) & 1u;                                  \
    const u32 _ho = ((w0o) >> mlane) & 1u;                                  \
    const u32 _le = ((w0e) >> m16) & 1u;                                    \
    const u32 _lo = ((w0o) >> m16) & 1u;                                    \
    const u32 _hpk = _he + (_ho << 16);                                     \
    const u32 _lpk = _le + (_lo << 16);                                     \
    aw  = __umul24(_hpk, 0x3F80u);                                          \
    b1w = __umul24(_lpk, 0x3F80u);                                          \
    b2w = (fp) & __umul24(_lpk, 0xFFFFu);                                   \
} while (0)

// ---------------------------------------------------------------------------
// Kernel 1: histogram via one-hot outer-product MFMA (no atomics — the
// lane-serial ds_add pipe was the R0 ceiling; R2 proved atomic+MFMA roles
// contend on the same LDS pipe, so pure-MFMA with a cheap build is the play).
// Per 32-voxel tile: counts += Phi^T*Plo, sums += Phi^T*(fg*Plo) via
// 16x16x32 bf16 MFMA. Each wave stages 256 voxels (mask word + packed fg
// pairs) in wave-private LDS, then 8 tiles of broadcast uint4 reads
// (16 lanes/group share addresses -> conflict-free broadcast).
// ---------------------------------------------------------------------------
__global__ __launch_bounds__(256) void histo_kernel(
    const float* __restrict__ pred,     // [B,2,V]
    const float* __restrict__ labmap,   // [B,1,V]
    float* __restrict__ ws_slots)       // [B*GRIDX][256] packed per-block hist
{
    __shared__ __align__(16) u32 s_w0[4][2][256];   // masks: per-wave dbuf
    __shared__ __align__(16) u32 s_fg[4][2][128];   // packed fg pairs

    const int b    = blockIdx.y;
    const int tid  = threadIdx.x;
    const int w    = tid >> 6;          // wave 0..3
    const int lane = tid & 63;
    const u32 mlane = (u32)(lane & 15); // A row / B col owned by this lane
    const u32 m16   = mlane + 16u;
    const int g    = lane >> 4;         // K-group 0..3

    const float4* p0 = (const float4*)(pred + (size_t)b * 2 * VOX);
    const float4* p1 = (const float4*)(pred + (size_t)b * 2 * VOX + VOX);
    const float4* lm = (const float4*)(labmap + (size_t)b * VOX);

    f32x4 accC = {0.f, 0.f, 0.f, 0.f};  // counts C[16][16]
    f32x4 accS = {0.f, 0.f, 0.f, 0.f};  // fg sums C[16][16]

    const int base = blockIdx.x * 256 + tid;

    #pragma unroll 2
    for (int it = 0; it < NITER; ++it) {
        const int i = base + it * (GRIDX * 256);
        const float4 a = p0[i];   // channel 0
        const float4 c = p1[i];   // channel 1
        const float4 l = lm[i];   // labels (exact integers 0..255 as float)

        u32 f0, f1, f2, f3, w00, w01, w02, w03;
        voxprep(a.x, c.x, l.x, f0, w00);
        voxprep(a.y, c.y, l.y, f1, w01);
        voxprep(a.z, c.z, l.z, f2, w02);
        voxprep(a.w, c.w, l.w, f3, w03);

        u32* stw = &s_w0[w][it & 1][0];
        u32* stf = &s_fg[w][it & 1][0];
        *(uint4*)(stw + (lane << 2)) = make_uint4(w00, w01, w02, w03);
        *(uint2*)(stf + (lane << 1)) = make_uint2(f0 + (f1 << 16),
                                                  f2 + (f3 << 16));
        // wave-private LDS, in-order per-wave ds pipe: no barrier needed

        const u32* rp = stw + (g << 3);      // this K-group's mask base
        const u32* rf = stf + (g << 2);      // this K-group's fg base
        #pragma unroll
        for (int t = 0; t < 8; ++t) {
            const uint4 q0 = *(const uint4*)(rp + t * 32);      // slots 0..3
            const uint4 q1 = *(const uint4*)(rp + t * 32 + 4);  // slots 4..7
            const uint4 fq = *(const uint4*)(rf + t * 16);      // fg pairs
            u32 a0, a1, a2, a3, b10, b11, b12, b13, b20, b21, b22, b23;
            PAIR2(q0.x, q0.y, fq.x, a0, b10, b20);
            PAIR2(q0.z, q0.w, fq.y, a1, b11, b21);
            PAIR2(q1.x, q1.y, fq.z, a2, b12, b22);
            PAIR2(q1.z, q1.w, fq.w, a3, b13, b23);
            FragU A, B1, B2;
            A.u  = make_uint4(a0, a1, a2, a3);
            B1.u = make_uint4(b10, b11, b12, b13);
            B2.u = make_uint4(b20, b21, b22, b23);
            accC = __builtin_amdgcn_mfma_f32_16x16x32_bf16(A.v, B1.v, accC, 0, 0, 0);
            accS = __builtin_amdgcn_mfma_f32_16x16x32_bf16(A.v, B2.v, accS, 0, 0, 0);
        }
    }

    // C/D layout (m89-verified): col = lane&15, row = (lane>>4)*4 + reg.
    // bin = row*16 + col. Reuse this wave's stage LDS as fold scratch
    // (in-wave ds ordering makes the overwrite safe).
    float* cnt_w = (float*)&s_w0[w][0][0];
    float* sum_w = (float*)&s_w0[w][1][0];
    const int row0 = (lane >> 4) << 2;
    const int colb = lane & 15;
    #pragma unroll
    for (int j = 0; j < 4; ++j) {
        cnt_w[(row0 + j) * 16 + colb] = accC[j];
        sum_w[(row0 + j) * 16 + colb] = accS[j];
    }
    __syncthreads();

    float cs = 0.0f, ss = 0.0f;
    #pragma unroll
    for (int ww = 0; ww < 4; ++ww) {
        cs += ((float*)&s_w0[ww][0][0])[tid];
        ss += ((float*)&s_w0[ww][1][0])[tid];
    }
    ws_slots[((size_t)(b * GRIDX + blockIdx.x)) * NLAB + tid] = ss + STEP * cs;
}

// ---------------------------------------------------------------------------
// Kernel 2: parallel slot reduction. Block r: batch = r/NPART, part = r%NPART;
// 256 threads = bins. Decode + sum GRIDX/NPART slots (coalesced 1KB rows).
// ---------------------------------------------------------------------------
__global__ __launch_bounds__(256) void reduce_kernel(
    const float* __restrict__ ws_slots, // [B*GRIDX][256]
    float* __restrict__ psum,           // [B*NPART][256]
    float* __restrict__ pcnt)           // [B*NPART][256]
{
    const int bin  = threadIdx.x;
    const int b    = blockIdx.x / NPART;
    const int part = blockIdx.x % NPART;
    const int per  = GRIDX / NPART;

    float cs = 0.0f, ss = 0.0f;
    for (int s = part * per; s < (part + 1) * per; ++s) {
        float v = ws_slots[((size_t)(b * GRIDX + s)) * NLAB + bin];
        float c = floorf(v * INV_STEP + 0.5f);   // exact count decode
        cs += c;
        ss += v - c * STEP;                      // packed fg sum
    }
    psum[(size_t)blockIdx.x * NLAB + bin] = ss;
    pcnt[(size_t)blockIdx.x * NLAB + bin] = cs;
}

// ---------------------------------------------------------------------------
// Kernel 3: fold partials, then masked softmin -> scalar loss.
// ---------------------------------------------------------------------------
__global__ __launch_bounds__(256) void scalar_kernel(
    const float* __restrict__ psum,     // [B*NPART][256]
    const float* __restrict__ pcnt,
    float* __restrict__ out)            // [1] loss
{
    __shared__ float s_fsum[BATCH][NLAB];
    __shared__ float s_fcnt[BATCH][NLAB];

    const int tid = threadIdx.x;        // 256 threads = bins

    for (int b = 0; b < BATCH; ++b) {
        float ss = 0.0f, cs = 0.0f;
        for (int p = 0; p < NPART; ++p) {
            ss += psum[(size_t)(b * NPART + p) * NLAB + tid];
            cs += pcnt[(size_t)(b * NPART + p) * NLAB + tid];
        }
        s_fsum[b][tid] = ss;
        s_fcnt[b][tid] = cs;
    }
    __syncthreads();

    if (tid < 64) {
        float total = 0.0f;
        float nbifs = 0.0f;
        if (tid >= 1) {  // bifs 1..63 (reference drops bif 0)
            for (int bb = 0; bb < BATCH; ++bb) {
                float means[3];
                bool  valid[3];
                int   nvalid = 0;
                for (int s = 0; s < 3; ++s) {
                    int lab = tid * 4 + 1 + s;   // stub s+1 (stub 0 dropped)
                    float cnt = s_fcnt[bb][lab];
                    float sum = s_fsum[bb][lab];
                    valid[s] = (cnt >= 1.0f);            // MIN_VOXELS = 1
                    means[s] = sum / fmaxf(cnt, 1.0f);
                    nvalid  += valid[s] ? 1 : 0;
                }
                float logits[3], m = -3e38f;
                for (int s = 0; s < 3; ++s) {
                    logits[s] = valid[s] ? (-means[s] / TEMP) : -1e9f;
                    m = fmaxf(m, logits[s]);
                }
                float e[3], se = 0.0f;
                for (int s = 0; s < 3; ++s) { e[s] = __expf(logits[s] - m); se += e[s]; }
                float score = 0.0f;
                for (int s = 0; s < 3; ++s) {
                    if (valid[s]) score += means[s] * (e[s] / se);
                }
                if (nvalid >= 2) {  // MIN_STUBS = 2
                    total += 1.0f - score;
                    nbifs += 1.0f;
                }
            }
        }
        for (int off = 32; off > 0; off >>= 1) {
            total += __shfl_down(total, off);
            nbifs += __shfl_down(nbifs, off);
        }
        if (tid == 0) {
            out[0] = (nbifs > 0.0f) ? (total / fmaxf(nbifs, 1.0f)) : 0.0f;
        }
    }
}

// ---------------------------------------------------------------------------
extern "C" void kernel_launch(void* const* d_in, const int* in_sizes, int n_in,
                              void* d_out, int out_size, void* d_ws, size_t ws_size,
                              hipStream_t stream) {
    const float* pred = (const float*)d_in[0];   // [B,C,D,H,W] fp32
    const float* lab  = (const float*)d_in[1];   // [B,1,D,H,W] fp32

    float* ws_slots = (float*)d_ws;                          // [B*GRIDX][256]
    float* psum = ws_slots + (size_t)BATCH * GRIDX * NLAB;   // [B*NPART][256]
    float* pcnt = psum + (size_t)BATCH * NPART * NLAB;       // [B*NPART][256]

    dim3 grid(GRIDX, BATCH);
    histo_kernel<<<grid, 256, 0, stream>>>(pred, lab, ws_slots);
    reduce_kernel<<<BATCH * NPART, 256, 0, stream>>>(ws_slots, psum, pcnt);
    scalar_kernel<<<1, 256, 0, stream>>>(psum, pcnt, (float*)d_out);
}

// Round 5
// 209.110 us; speedup vs baseline: 1.0742x; 1.0086x over previous
//
#include <hip/hip_runtime.h>
#include <math.h>

// Problem constants (from reference)
#define BATCH     2
#define NLAB      256            // 64 bifs * 4 stubs
#define VOX       (192*192*192)  // 7,077,888 voxels per batch
#define TEMP      0.2f
#define GRIDX     768            // blocks per batch (1536 blocks = 6/CU even)
#define NITER     ((VOX/4)/(GRIDX*256))   // = 9 exact
#define NPART     16             // reduce parts per batch

// Packed slot: value = sum_fg + STEP*count. Per block 9216 voxels (~36/bin,
// max ~150): packed <= ~600K << 2^24 -> count decodes exactly; fg rounding
// noise ~1e-4 relative on batch-bin means (threshold 1e-2; R1/R3 absmax 0.0).
#define STEP      4096.0f
#define INV_STEP  (1.0f/4096.0f)

typedef unsigned int u32;
typedef __attribute__((ext_vector_type(8))) short bf16x8;   // 8 bf16 (4 VGPRs)
typedef __attribute__((ext_vector_type(4))) float f32x4;    // MFMA C/D
union FragU { uint4 u; bf16x8 v; };

// fg = sigmoid(p1-p0) (C==2 softmax ch1), RNE -> bf16 in low 16 bits.
__device__ __forceinline__ u32 fgbf16(float pa, float pc) {
    const float fg = __builtin_amdgcn_rcpf(1.0f + __expf(pa - pc));
    u32 bits = __float_as_uint(fg);
    bits += 0x7FFFu + ((bits >> 16) & 1u);            // RNE to bf16
    return bits >> 16;
}

// one-hot masks for a voxel's label: hm = 1<<hi4, lm = 1<<lo4 (bin=hi*16+lo)
__device__ __forceinline__ void voxmask(float pl, u32& hm, u32& lmm) {
    const u32 lab = ((u32)(int)(pl + 0.5f)) & 255u;
    hm  = 1u << (lab >> 4);
    lmm = 1u << (lab & 15u);
}

// Fragment build, one voxel-PAIR (2 K-slots) per call. whi/wlo carry the
// pair's one-hot masks (even in low16, odd in high16), so the lane's match
// bits for BOTH slots come from ONE shift + ONE and (0x10001) — 8 VALU/pair
// vs R3's 10 (R1's ~19). Same one-hot bf16 values as the verified R1/R3
// build -> numerics identical.
#define PAIRH(whi, wlo, fp, aw, b1w, b2w) do {                              \
    const u32 _h = ((whi) >> mlane) & 0x10001u;                             \
    const u32 _l = ((wlo) >> mlane) & 0x10001u;                             \
    aw  = __umul24(_h, 0x3F80u);                                            \
    b1w = __umul24(_l, 0x3F80u);                                            \
    b2w = (fp) & __umul24(_l, 0xFFFFu);                                     \
} while (0)

// ---------------------------------------------------------------------------
// Kernel 1: histogram via one-hot outer-product MFMA (no atomics).
// Per 32-voxel tile: counts += Phi^T*Plo, sums += Phi^T*(fg*Plo) via
// 16x16x32 bf16 MFMA. Wave stages 256 voxels/iter in wave-private LDS
// (interleaved (whi,wlo) words + packed fg pairs), then 8 tiles of broadcast
// uint4 reads (16 lanes/group share addresses -> conflict-free).
// R3 post-mortem: VGPR=20 -> serial load chain, ~27us stall. This version
// prefetches iter it+1's global loads across the tile phase (1-deep manual
// pipeline; clamped index keeps the load unconditional so the scheduler
// can't sink it behind a branch).
// ---------------------------------------------------------------------------
__global__ __launch_bounds__(256) void histo_kernel(
    const float* __restrict__ pred,     // [B,2,V]
    const float* __restrict__ labmap,   // [B,1,V]
    float* __restrict__ ws_slots)       // [B*GRIDX][256] packed per-block hist
{
    __shared__ __align__(16) u32 s_iv[4][2][256];   // (whi,wlo) per pair
    __shared__ __align__(16) u32 s_fg[4][2][128];   // packed fg pairs

    const int b    = blockIdx.y;
    const int tid  = threadIdx.x;
    const int w    = tid >> 6;          // wave 0..3
    const int lane = tid & 63;
    const u32 mlane = (u32)(lane & 15); // A row / B col owned by this lane
    const int g    = lane >> 4;         // K-group 0..3

    const float4* p0 = (const float4*)(pred + (size_t)b * 2 * VOX);
    const float4* p1 = (const float4*)(pred + (size_t)b * 2 * VOX + VOX);
    const float4* lm = (const float4*)(labmap + (size_t)b * VOX);

    f32x4 accC = {0.f, 0.f, 0.f, 0.f};  // counts C[16][16]
    f32x4 accS = {0.f, 0.f, 0.f, 0.f};  // fg sums C[16][16]

    const int base = blockIdx.x * 256 + tid;

    // --- 1-deep global prefetch pipeline ---
    float4 a = p0[base];
    float4 c = p1[base];
    float4 l = lm[base];

    for (int it = 0; it < NITER; ++it) {
        // Issue next iteration's loads NOW; ~900cy tile phase hides them.
        const int nit = (it + 1 < NITER) ? (it + 1) : it;
        const int inx = base + nit * (GRIDX * 256);
        const float4 an = p0[inx];
        const float4 cn = p1[inx];
        const float4 ln = lm[inx];

        // Pack current iteration (pair-packed masks + fg).
        u32 hm0, lm0, hm1, lm1, hm2, lm2, hm3, lm3;
        voxmask(l.x, hm0, lm0);
        voxmask(l.y, hm1, lm1);
        voxmask(l.z, hm2, lm2);
        voxmask(l.w, hm3, lm3);
        const u32 whiA = hm0 | (hm1 << 16);   // pair 0 (vox x,y)
        const u32 wloA = lm0 | (lm1 << 16);
        const u32 whiB = hm2 | (hm3 << 16);   // pair 1 (vox z,w)
        const u32 wloB = lm2 | (lm3 << 16);
        const u32 fgA  = fgbf16(a.x, c.x) | (fgbf16(a.y, c.y) << 16);
        const u32 fgB  = fgbf16(a.z, c.z) | (fgbf16(a.w, c.w) << 16);

        u32* iv  = &s_iv[w][it & 1][0];
        u32* fgp = &s_fg[w][it & 1][0];
        *(uint4*)(iv + (lane << 2)) = make_uint4(whiA, wloA, whiB, wloB);
        *(uint2*)(fgp + (lane << 1)) = make_uint2(fgA, fgB);
        // wave-private LDS, in-order per-wave ds pipe: no barrier needed

        const u32* rp = iv + (g << 3);      // this K-group's mask base
        const u32* rf = fgp + (g << 2);     // this K-group's fg base
        #pragma unroll
        for (int t = 0; t < 8; ++t) {
            const uint4 q0 = *(const uint4*)(rp + t * 32);      // pairs 0,1
            const uint4 q1 = *(const uint4*)(rp + t * 32 + 4);  // pairs 2,3
            const uint4 fq = *(const uint4*)(rf + t * 16);      // fg pairs
            u32 a0, a1, a2, a3, b10, b11, b12, b13, b20, b21, b22, b23;
            PAIRH(q0.x, q0.y, fq.x, a0, b10, b20);
            PAIRH(q0.z, q0.w, fq.y, a1, b11, b21);
            PAIRH(q1.x, q1.y, fq.z, a2, b12, b22);
            PAIRH(q1.z, q1.w, fq.w, a3, b13, b23);
            FragU A, B1, B2;
            A.u  = make_uint4(a0, a1, a2, a3);
            B1.u = make_uint4(b10, b11, b12, b13);
            B2.u = make_uint4(b20, b21, b22, b23);
            accC = __builtin_amdgcn_mfma_f32_16x16x32_bf16(A.v, B1.v, accC, 0, 0, 0);
            accS = __builtin_amdgcn_mfma_f32_16x16x32_bf16(A.v, B2.v, accS, 0, 0, 0);
        }

        a = an; c = cn; l = ln;
    }

    // C/D layout (m89-verified): col = lane&15, row = (lane>>4)*4 + reg.
    // bin = row*16 + col. Reuse stage LDS as fold scratch (in-wave ds
    // ordering makes the overwrite safe).
    float* cnt_w = (float*)&s_iv[w][0][0];
    float* sum_w = (float*)&s_iv[w][1][0];
    const int row0 = (lane >> 4) << 2;
    const int colb = lane & 15;
    #pragma unroll
    for (int j = 0; j < 4; ++j) {
        cnt_w[(row0 + j) * 16 + colb] = accC[j];
        sum_w[(row0 + j) * 16 + colb] = accS[j];
    }
    __syncthreads();

    float cs = 0.0f, ss = 0.0f;
    #pragma unroll
    for (int ww = 0; ww < 4; ++ww) {
        cs += ((float*)&s_iv[ww][0][0])[tid];
        ss += ((float*)&s_iv[ww][1][0])[tid];
    }
    ws_slots[((size_t)(b * GRIDX + blockIdx.x)) * NLAB + tid] = ss + STEP * cs;
}

// ---------------------------------------------------------------------------
// Kernel 2: parallel slot reduction. Block r: batch = r/NPART, part = r%NPART;
// 256 threads = bins. Decode + sum GRIDX/NPART slots (coalesced 1KB rows).
// ---------------------------------------------------------------------------
__global__ __launch_bounds__(256) void reduce_kernel(
    const float* __restrict__ ws_slots, // [B*GRIDX][256]
    float* __restrict__ psum,           // [B*NPART][256]
    float* __restrict__ pcnt)           // [B*NPART][256]
{
    const int bin  = threadIdx.x;
    const int b    = blockIdx.x / NPART;
    const int part = blockIdx.x % NPART;
    const int per  = GRIDX / NPART;

    float cs = 0.0f, ss = 0.0f;
    for (int s = part * per; s < (part + 1) * per; ++s) {
        float v = ws_slots[((size_t)(b * GRIDX + s)) * NLAB + bin];
        float c = floorf(v * INV_STEP + 0.5f);   // exact count decode
        cs += c;
        ss += v - c * STEP;                      // packed fg sum
    }
    psum[(size_t)blockIdx.x * NLAB + bin] = ss;
    pcnt[(size_t)blockIdx.x * NLAB + bin] = cs;
}

// ---------------------------------------------------------------------------
// Kernel 3: fold partials, then masked softmin -> scalar loss.
// ---------------------------------------------------------------------------
__global__ __launch_bounds__(256) void scalar_kernel(
    const float* __restrict__ psum,     // [B*NPART][256]
    const float* __restrict__ pcnt,
    float* __restrict__ out)            // [1] loss
{
    __shared__ float s_fsum[BATCH][NLAB];
    __shared__ float s_fcnt[BATCH][NLAB];

    const int tid = threadIdx.x;        // 256 threads = bins

    for (int b = 0; b < BATCH; ++b) {
        float ss = 0.0f, cs = 0.0f;
        for (int p = 0; p < NPART; ++p) {
            ss += psum[(size_t)(b * NPART + p) * NLAB + tid];
            cs += pcnt[(size_t)(b * NPART + p) * NLAB + tid];
        }
        s_fsum[b][tid] = ss;
        s_fcnt[b][tid] = cs;
    }
    __syncthreads();

    if (tid < 64) {
        float total = 0.0f;
        float nbifs = 0.0f;
        if (tid >= 1) {  // bifs 1..63 (reference drops bif 0)
            for (int bb = 0; bb < BATCH; ++bb) {
                float means[3];
                bool  valid[3];
                int   nvalid = 0;
                for (int s = 0; s < 3; ++s) {
                    int lab = tid * 4 + 1 + s;   // stub s+1 (stub 0 dropped)
                    float cnt = s_fcnt[bb][lab];
                    float sum = s_fsum[bb][lab];
                    valid[s] = (cnt >= 1.0f);            // MIN_VOXELS = 1
                    means[s] = sum / fmaxf(cnt, 1.0f);
                    nvalid  += valid[s] ? 1 : 0;
                }
                float logits[3], m = -3e38f;
                for (int s = 0; s < 3; ++s) {
                    logits[s] = valid[s] ? (-means[s] / TEMP) : -1e9f;
                    m = fmaxf(m, logits[s]);
                }
                float e[3], se = 0.0f;
                for (int s = 0; s < 3; ++s) { e[s] = __expf(logits[s] - m); se += e[s]; }
                float score = 0.0f;
                for (int s = 0; s < 3; ++s) {
                    if (valid[s]) score += means[s] * (e[s] / se);
                }
                if (nvalid >= 2) {  // MIN_STUBS = 2
                    total += 1.0f - score;
                    nbifs += 1.0f;
                }
            }
        }
        for (int off = 32; off > 0; off >>= 1) {
            total += __shfl_down(total, off);
            nbifs += __shfl_down(nbifs, off);
        }
        if (tid == 0) {
            out[0] = (nbifs > 0.0f) ? (total / fmaxf(nbifs, 1.0f)) : 0.0f;
        }
    }
}

// ---------------------------------------------------------------------------
extern "C" void kernel_launch(void* const* d_in, const int* in_sizes, int n_in,
                              void* d_out, int out_size, void* d_ws, size_t ws_size,
                              hipStream_t stream) {
    const float* pred = (const float*)d_in[0];   // [B,C,D,H,W] fp32
    const float* lab  = (const float*)d_in[1];   // [B,1,D,H,W] fp32

    float* ws_slots = (float*)d_ws;                          // [B*GRIDX][256]
    float* psum = ws_slots + (size_t)BATCH * GRIDX * NLAB;   // [B*NPART][256]
    float* pcnt = psum + (size_t)BATCH * NPART * NLAB;       // [B*NPART][256]

    dim3 grid(GRIDX, BATCH);
    histo_kernel<<<grid, 256, 0, stream>>>(pred, lab, ws_slots);
    reduce_kernel<<<BATCH * NPART, 256, 0, stream>>>(ws_slots, psum, pcnt);
    scalar_kernel<<<1, 256, 0, stream>>>(psum, pcnt, (float*)d_out);
}